// Round 6
// baseline (240.524 us; speedup 1.0000x reference)
//
#include <hip/hip_runtime.h>
#include <math.h>

#define BNTOT 8192      // B*N
#define CH    64        // channels
#define KP1   11        // K+1 neighbors
#define NLOC  1568      // B * E  (8 * 196)
#define MARGIN 1.0f     // bf16 score-error margin for the filter (>= ~0.4 tail err)
#define LCAPR 512       // per-row candidate capacity, fast path (fallback: full scan)

typedef __attribute__((ext_vector_type(8))) short short8;   // 8 bf16 (4 VGPRs)
typedef __attribute__((ext_vector_type(4))) float float4v;  // MFMA C/D

// ---------- helpers ----------
__device__ __forceinline__ int pcnt(int p) {
  int lo = p - 4; if (lo < 0) lo = 0; lo += (lo & 1);
  int hi = p; if (hi > 26) hi = 26;
  return (hi >= lo) ? (((hi - lo) >> 1) + 1) : 0;
}
__device__ __forceinline__ float dv2_of(int u) {
  int node = u & 1023;
  int rr = node >> 5, cc = node & 31;
  int dv = KP1 + pcnt(rr) * pcnt(cc);
  return 1.0f / sqrtf((float)dv);
}
__device__ __forceinline__ unsigned short f2bf(float f) {   // RNE fp32->bf16
  unsigned u = __float_as_uint(f);
  unsigned r = (u + 0x7FFFu + ((u >> 16) & 1u)) >> 16;
  return (unsigned short)r;
}
// monotone u32 key: flip fp32 bits so unsigned compare == float compare
__device__ __forceinline__ unsigned fkey(float s) {
  unsigned u = __float_as_uint(s);
  return (u & 0x80000000u) ? ~u : (u | 0x80000000u);
}
// monotone u64 (score,idx) key for the fallback path
__device__ __forceinline__ unsigned long long skey(float s, int idx) {
  return ((unsigned long long)fkey(s) << 32) | (unsigned)idx;
}
__device__ __forceinline__ int mbcnt64(unsigned long long m) {  // set bits below my lane
  return __builtin_amdgcn_mbcnt_hi((unsigned)(m >> 32),
         __builtin_amdgcn_mbcnt_lo((unsigned)m, 0));
}
// wave-wide sum of per-lane value l in [0,8] via 4 ballots (no DS ops)
__device__ __forceinline__ int wave_count4(int l) {
  return     __popcll(__ballot(l & 1))
       + 2 * __popcll(__ballot(l & 2))
       + 4 * __popcll(__ballot(l & 4))
       + 8 * __popcll(__ballot(l & 8));
}

// ---------- K0: cast to bf16 + row squared norms (fused) ----------
__global__ void k_cast(const float* __restrict__ X, unsigned short* __restrict__ Xh,
                       float* __restrict__ sq) {
  int g = blockIdx.x * 256 + threadIdx.x;
  int lane = threadIdx.x & 63;
  float v = X[g];
  Xh[g] = f2bf(v);
  float s = v * v;
  #pragma unroll
  for (int off = 32; off >= 1; off >>= 1) s += __shfl_xor(s, off, 64);
  if (lane == 0) sq[g >> 6] = s;
}

// ---------- KA1: partial per-row top-11 over a subsampled chunk ----------
// grid 1024 = 128 row-groups x 8 chunks; block 256 = 4 waves.
__global__ __launch_bounds__(256)
void k_thrpart(const float* __restrict__ X, const float* __restrict__ sq,
               float* __restrict__ part) {
  const int tid = threadIdx.x, wave = tid >> 6, lane = tid & 63;
  const int rg = blockIdx.x >> 3, chunk = blockIdx.x & 7;
  const int row = rg * 64 + lane;
  float xr[CH];
  {
    const float4* xp = (const float4*)(X + (size_t)row * CH);
    #pragma unroll
    for (int k = 0; k < CH / 4; ++k) {
      float4 v = xp[k];
      xr[4*k+0] = v.x; xr[4*k+1] = v.y; xr[4*k+2] = v.z; xr[4*k+3] = v.w;
    }
  }
  float tv[KP1];
  #pragma unroll
  for (int t = 0; t < KP1; ++t) tv[t] = INFINITY;

  for (int s = 0; s < 32; ++s) {
    int j = __builtin_amdgcn_readfirstlane(((chunk * 4 + wave) * 32 + s) * 8);
    const float* cp = X + (size_t)j * CH;
    float d0 = 0.f, d1 = 0.f, d2 = 0.f, d3 = 0.f;
    #pragma unroll
    for (int k = 0; k < CH / 4; ++k) {
      d0 = fmaf(xr[4*k+0], cp[4*k+0], d0);
      d1 = fmaf(xr[4*k+1], cp[4*k+1], d1);
      d2 = fmaf(xr[4*k+2], cp[4*k+2], d2);
      d3 = fmaf(xr[4*k+3], cp[4*k+3], d3);
    }
    float cv = fmaf(-2.0f, (d0 + d1) + (d2 + d3), sq[j]);
    #pragma unroll
    for (int t = 0; t < KP1; ++t) {
      float lo = fminf(tv[t], cv), hi = fmaxf(tv[t], cv);
      tv[t] = lo; cv = hi;
    }
  }
  __shared__ float ls[4][64][KP1];
  #pragma unroll
  for (int t = 0; t < KP1; ++t) ls[wave][lane][t] = tv[t];
  __syncthreads();
  if (tid < 64) {
    float v[KP1];
    #pragma unroll
    for (int t = 0; t < KP1; ++t) v[t] = ls[0][tid][t];
    #pragma unroll
    for (int w = 1; w < 4; ++w)
      #pragma unroll
      for (int t = 0; t < KP1; ++t) {
        float cv = ls[w][tid][t];
        #pragma unroll
        for (int s2 = 0; s2 < KP1; ++s2) {
          float lo = fminf(v[s2], cv), hi = fmaxf(v[s2], cv);
          v[s2] = lo; cv = hi;
        }
      }
    size_t base = ((size_t)blockIdx.x * 64 + tid) * KP1;
    #pragma unroll
    for (int t = 0; t < KP1; ++t) part[base + t] = v[t];
  }
}

// ---------- KA2: merge 8 chunk-partials -> per-row threshold ----------
__global__ void k_thrmerge(const float* __restrict__ part, float* __restrict__ thr) {
  const int rg = blockIdx.x, lane = threadIdx.x;
  const int row = rg * 64 + lane;
  float v[KP1];
  {
    size_t b0 = ((size_t)(rg * 8) * 64 + lane) * KP1;
    #pragma unroll
    for (int t = 0; t < KP1; ++t) v[t] = part[b0 + t];
  }
  for (int c = 1; c < 8; ++c) {
    size_t b = ((size_t)(rg * 8 + c) * 64 + lane) * KP1;
    #pragma unroll
    for (int t = 0; t < KP1; ++t) {
      float cv = part[b + t];
      #pragma unroll
      for (int s2 = 0; s2 < KP1; ++s2) {
        float lo = fminf(v[s2], cv), hi = fmaxf(v[s2], cv);
        v[s2] = lo; cv = hi;
      }
    }
  }
  thr[row] = v[KP1 - 1] + MARGIN;
}

// ---------- KB: MFMA all-pairs scores -> candidate BITMASK (branch-free) ----------
// grid 4096 = 128 row-tiles(64 rows) x 32 col-tiles(256 cols); block 256 = 4 waves.
__global__ __launch_bounds__(256)
void k_filter(const unsigned short* __restrict__ Xh, const float* __restrict__ sq,
              const float* __restrict__ thr, unsigned long long* __restrict__ mask) {
  const int tid = threadIdx.x, wave = tid >> 6, lane = tid & 63;
  const int m = lane & 15, q = lane >> 4;
  const int rowbase = (blockIdx.x >> 5) * 64;
  const int colbase = (blockIdx.x & 31) * 256 + wave * 64;
  const int wcol = (blockIdx.x & 31) * 4 + wave;   // u64-word column index

  // A fragments: 4 row-subtiles x 2 k-chunks (32 VGPRs)
  short8 a[4][2];
  #pragma unroll
  for (int rt = 0; rt < 4; ++rt)
    #pragma unroll
    for (int kc = 0; kc < 2; ++kc)
      a[rt][kc] = *(const short8*)(Xh + (size_t)(rowbase + rt * 16 + m) * CH + kc * 32 + q * 8);

  // B tiles for all 4 sub-cols + col norms: one load burst
  short8 b0[4], b1[4];
  float sqv[4];
  #pragma unroll
  for (int sub = 0; sub < 4; ++sub) {
    const int coln = colbase + sub * 16 + m;
    const short8* bp = (const short8*)(Xh + (size_t)coln * CH + q * 8);
    b0[sub] = bp[0];
    b1[sub] = bp[4];               // +32 bf16
    sqv[sub] = sq[coln];
  }

  float thrv[16];
  #pragma unroll
  for (int rt = 0; rt < 4; ++rt)
    #pragma unroll
    for (int r = 0; r < 4; ++r)
      thrv[rt * 4 + r] = thr[rowbase + rt * 16 + q * 4 + r];

  const float4v cz = {0.f, 0.f, 0.f, 0.f};
  // lane ℓ (within its 16-lane slot) assembles+stores the word for row rt*16+sr
  const int sr = lane & 15, qq = sr >> 2, rr = sr & 3;

  #pragma unroll
  for (int rt = 0; rt < 4; ++rt) {
    unsigned long long bal[4][4];
    #pragma unroll
    for (int sub = 0; sub < 4; ++sub) {
      float4v c = __builtin_amdgcn_mfma_f32_16x16x32_bf16(a[rt][0], b0[sub], cz, 0, 0, 0);
      c = __builtin_amdgcn_mfma_f32_16x16x32_bf16(a[rt][1], b1[sub], c, 0, 0, 0);
      #pragma unroll
      for (int r = 0; r < 4; ++r) {
        float score = fmaf(-2.0f, c[r], sqv[sub]);
        bal[sub][r] = __ballot(score < thrv[rt * 4 + r]);
      }
    }
    // bit (sub*16+m) of row (rt*16 + q*4 + r) is ballot bit q*16+m
    unsigned long long w = 0;
    #pragma unroll
    for (int sub = 0; sub < 4; ++sub) {
      unsigned long long bsel = (rr == 0) ? bal[sub][0]
                              : (rr == 1) ? bal[sub][1]
                              : (rr == 2) ? bal[sub][2]
                              :             bal[sub][3];
      unsigned long long slice = (bsel >> (qq * 16)) & 0xFFFFull;
      w |= slice << (sub * 16);
    }
    if ((lane >> 4) == rt)
      mask[(size_t)(rowbase + rt * 16 + sr) * 128 + wcol] = w;
  }
}

// ---------- KC: exact rescore from bitmask, one wave per row ----------
// Ballot-bisection selection (R5-proven, zero DS cross-lane traffic).
// This round: LCAPR 256->512 (fallback tail was the straggler cost) and the
// slot loop statically unrolled to 8 guarded iterations so all LDS col-reads +
// global gathers issue as one batch (no serial load->use chain across a
// runtime-trip loop). Fallback full scan kept as safety net only.
__global__ __launch_bounds__(256)
void k_rescore(const float* __restrict__ X, const float* __restrict__ sq,
               const unsigned long long* __restrict__ mask,
               int* __restrict__ inds, int* __restrict__ DE) {
  __shared__ int cols[4][LCAPR];
  const int tid = threadIdx.x, lane = tid & 63, wv = tid >> 6;
  const int row = __builtin_amdgcn_readfirstlane(blockIdx.x * 4 + wv);

  // own row (wave-uniform address -> scalar loads)
  float xr[CH];
  {
    const float4* xp = (const float4*)(X + (size_t)row * CH);
    #pragma unroll
    for (int k = 0; k < CH / 4; ++k) {
      float4 v = xp[k];
      xr[4*k+0] = v.x; xr[4*k+1] = v.y; xr[4*k+2] = v.z; xr[4*k+3] = v.w;
    }
  }

  // mask row: lane owns columns [lane*128, lane*128+128)
  const unsigned long long* mrow = mask + (size_t)row * 128;
  unsigned long long w0 = mrow[lane * 2 + 0];
  unsigned long long w1 = mrow[lane * 2 + 1];

  // compaction prefix via ballots (cnt <= 128 -> 8 bits); zero DS ops
  int cnt = __popcll(w0) + __popcll(w1);
  int p = 0, total = 0;
  #pragma unroll
  for (int b = 0; b < 8; ++b) {
    unsigned long long bb = __ballot((cnt >> b) & 1);
    p     += mbcnt64(bb) << b;      // exclusive prefix (lanes below me)
    total += __popcll(bb) << b;
  }

  if (total <= LCAPR) {
    // scatter my candidate columns (few ds_writes, wave-private region)
    unsigned long long w = w0;
    while (w) { int b = __builtin_ctzll(w); w &= w - 1; cols[wv][p++] = lane * 128 + b; }
    w = w1;
    while (w) { int b = __builtin_ctzll(w); w &= w - 1; cols[wv][p++] = lane * 128 + 64 + b; }

    // exact dots -> per-lane register keys (8 static slots, batched issue)
    unsigned kscore[8]; int kidx[8];
    #pragma unroll
    for (int a = 0; a < 8; ++a) { kscore[a] = 0xFFFFFFFFu; kidx[a] = 0; }
    #pragma unroll
    for (int a = 0; a < 8; ++a) {
      int s = a * 64 + lane;
      bool valid = s < total;
      int cj = cols[wv][valid ? s : 0];
      const float4* cp = (const float4*)(X + (size_t)cj * CH);
      float d0 = 0.f, d1 = 0.f, d2 = 0.f, d3 = 0.f;
      #pragma unroll
      for (int k = 0; k < CH / 4; ++k) {
        float4 v = cp[k];
        d0 = fmaf(xr[4*k+0], v.x, d0);
        d1 = fmaf(xr[4*k+1], v.y, d1);
        d2 = fmaf(xr[4*k+2], v.z, d2);
        d3 = fmaf(xr[4*k+3], v.w, d3);
      }
      float score = fmaf(-2.0f, (d0 + d1) + (d2 + d3), sq[cj]);
      if (valid) { kscore[a] = fkey(score); kidx[a] = cj; }
    }

    // 32-round bisection on u32 score key: find largest T with cntLT(T) < 11
    unsigned long long blo = 0, bhi = 1ull << 32;
    for (int it = 0; it < 32; ++it) {
      unsigned mid = (unsigned)((blo + bhi) >> 1);
      int l = 0;
      #pragma unroll
      for (int a = 0; a < 8; ++a) l += (kscore[a] < mid);
      if (wave_count4(l) < KP1) blo = mid; else bhi = mid;
    }
    const unsigned T = (unsigned)blo;

    // counts at the threshold
    int ll = 0, le = 0;
    #pragma unroll
    for (int a = 0; a < 8; ++a) { ll += (kscore[a] < T); le += (kscore[a] <= T); }
    int c_less = wave_count4(ll);
    int c_le   = wave_count4(le);
    const int needed = KP1 - c_less;          // >= 1
    const int cnt_eq = c_le - c_less;         // >= needed

    unsigned idxcut = BNTOT;                  // take all eq by default
    if (cnt_eq != needed) {                   // boundary score tie: pick lowest idx
      int lo2 = 0, hi2 = BNTOT;
      for (int it = 0; it < 13; ++it) {
        int mid2 = (lo2 + hi2) >> 1;
        int l2 = 0;
        #pragma unroll
        for (int a = 0; a < 8; ++a) l2 += ((kscore[a] == T) & (kidx[a] < mid2));
        if (wave_count4(l2) < needed) lo2 = mid2; else hi2 = mid2;
      }
      idxcut = (unsigned)hi2;                 // idx < idxcut among eq wins
    }

    // emit 11 winners: position via ballot + mbcnt prefix, per slot
    int base = 0;
    #pragma unroll
    for (int a = 0; a < 8; ++a) {
      bool win = (kscore[a] < T) | ((kscore[a] == T) & ((unsigned)kidx[a] < idxcut));
      unsigned long long bal = __ballot(win);
      int pos = base + mbcnt64(bal);
      if (win) {
        inds[(size_t)row * KP1 + pos] = kidx[a];
        atomicAdd(&DE[kidx[a]], 1);
      }
      base += __popcll(bal);
    }
  } else {
    // Fallback: exact full scan + sorted-11 insert + 11 wave-min extractions
    float tv[KP1]; int ti[KP1];
    #pragma unroll
    for (int t = 0; t < KP1; ++t) { tv[t] = INFINITY; ti[t] = -1; }
    for (int s = lane; s < BNTOT; s += 64) {
      const float4* cp = (const float4*)(X + (size_t)s * CH);
      float d0 = 0.f, d1 = 0.f, d2 = 0.f, d3 = 0.f;
      #pragma unroll
      for (int k = 0; k < CH / 4; ++k) {
        float4 v = cp[k];
        d0 = fmaf(xr[4*k+0], v.x, d0);
        d1 = fmaf(xr[4*k+1], v.y, d1);
        d2 = fmaf(xr[4*k+2], v.z, d2);
        d3 = fmaf(xr[4*k+3], v.w, d3);
      }
      float score = fmaf(-2.0f, (d0 + d1) + (d2 + d3), sq[s]);
      if (score < tv[KP1 - 1]) {
        float cv = score; int ci = s;
        #pragma unroll
        for (int t = 0; t < KP1; ++t) {
          bool sw = cv < tv[t];
          float nv = sw ? cv    : tv[t]; int ni = sw ? ci    : ti[t];
          float ov = sw ? tv[t] : cv;    int oi = sw ? ti[t] : ci;
          tv[t] = nv; ti[t] = ni; cv = ov; ci = oi;
        }
      }
    }
    unsigned long long cur = skey(tv[0], ti[0]);
    unsigned long long keep = 0;
    #pragma unroll
    for (int t = 0; t < KP1; ++t) {
      unsigned long long mw = cur;
      #pragma unroll
      for (int off = 1; off < 64; off <<= 1) {
        unsigned lo = __shfl_xor((unsigned)mw, off, 64);
        unsigned hi = __shfl_xor((unsigned)(mw >> 32), off, 64);
        unsigned long long o = ((unsigned long long)hi << 32) | lo;
        mw = (o < mw) ? o : mw;
      }
      if (lane == t) keep = mw;
      if (cur == mw) {
        #pragma unroll
        for (int q = 0; q < KP1 - 1; ++q) { tv[q] = tv[q+1]; ti[q] = ti[q+1]; }
        tv[KP1-1] = INFINITY; ti[KP1-1] = -1;
        cur = skey(tv[0], ti[0]);
      }
    }
    if (lane < KP1) {
      int idx = (int)(unsigned)(keep & 0xFFFFFFFFull);
      inds[(size_t)row * KP1 + lane] = idx;
      atomicAdd(&DE[idx], 1);
    }
  }
}

// ---------- K3: t = Dv^{-1/2} * (x @ W^T + b) ----------
// grid 512: 4 waves/block x 4 rows/wave.
__global__ void k_lin(const float* __restrict__ X, const float* __restrict__ W,
                      const float* __restrict__ bias, float* __restrict__ t) {
  int lane = threadIdx.x & 63;
  int wave = threadIdx.x >> 6;
  int rowbase = (blockIdx.x * 4 + wave) * 4;
  float wr[CH];
  {
    const float4* wp = (const float4*)(W + (size_t)lane * CH);
    #pragma unroll
    for (int k = 0; k < CH / 4; ++k) {
      float4 v = wp[k];
      wr[4*k+0] = v.x; wr[4*k+1] = v.y; wr[4*k+2] = v.z; wr[4*k+3] = v.w;
    }
  }
  float bc = bias[lane];
  #pragma unroll
  for (int r = 0; r < 4; ++r) {
    int row = __builtin_amdgcn_readfirstlane(rowbase + r);
    const float* xp = X + (size_t)row * CH;
    float d0 = 0.f, d1 = 0.f, d2 = 0.f, d3 = 0.f;
    #pragma unroll
    for (int k = 0; k < CH / 4; ++k) {
      d0 = fmaf(wr[4*k+0], xp[4*k+0], d0);
      d1 = fmaf(wr[4*k+1], xp[4*k+1], d1);
      d2 = fmaf(wr[4*k+2], xp[4*k+2], d2);
      d3 = fmaf(wr[4*k+3], xp[4*k+3], d3);
    }
    float y = (d0 + d1) + (d2 + d3) + bc;
    t[(size_t)row * CH + lane] = y * dv2_of(row);
  }
}

// ---------- K4: fused edge sums — scatter (KNN, atomics) + local patches ----------
// grid 2048+392: first 2048 blocks = scatter (4 nodes each), rest = local (4 edges each).
__global__ void k_edge(const float* __restrict__ t, const int* __restrict__ inds,
                       float* __restrict__ s_knn, float* __restrict__ s_loc) {
  int c = threadIdx.x & 63;
  int w = threadIdx.x >> 6;
  if (blockIdx.x < BNTOT / 4) {
    int u = blockIdx.x * 4 + w;
    float val = t[(size_t)u * CH + c];
    int ub = __builtin_amdgcn_readfirstlane(u);
    const int* ip = inds + (size_t)ub * KP1;
    #pragma unroll
    for (int j = 0; j < KP1; ++j) {
      int e = ip[j];
      atomicAdd(&s_knn[(size_t)e * CH + c], val);
    }
  } else {
    int e = (blockIdx.x - BNTOT / 4) * 4 + w;
    int b  = e / 196;
    int le = e - b * 196;
    int pi = le / 14;
    int pj = le - pi * 14;
    int base = b * 1024 + (pi * 2) * 32 + pj * 2;
    float acc = 0.f;
    #pragma unroll
    for (int di = 0; di < 5; ++di)
      #pragma unroll
      for (int dj = 0; dj < 5; ++dj)
        acc += t[(size_t)(base + di * 32 + dj) * CH + c];
    s_loc[(size_t)e * CH + c] = acc * (1.0f / 25.0f);
  }
}

// ---------- K5: gather + BN partials -> 8 atomic bins (k_bnfin1 fused away) ----------
__global__ void k_gatherbn(const float* __restrict__ s_knn, const float* __restrict__ s_loc,
                           const int* __restrict__ inds, const int* __restrict__ DE,
                           float* __restrict__ z, float* __restrict__ gsum,
                           float* __restrict__ gsumsq) {
  int c = threadIdx.x & 63;
  int w = threadIdx.x >> 6;
  int u = blockIdx.x * 4 + w;
  int ub = __builtin_amdgcn_readfirstlane(u);
  const int* ip = inds + (size_t)ub * KP1;
  float acc = 0.f;
  #pragma unroll
  for (int j = 0; j < KP1; ++j) {
    int e = ip[j];
    float invde = 1.0f / (float)DE[e];
    acc += s_knn[(size_t)e * CH + c] * invde;
  }
  int node = ub & 1023, b = ub >> 10;
  int rr = node >> 5, cc = node & 31;
  int i0 = rr - 4; if (i0 < 0) i0 = 0; i0 += (i0 & 1);
  int i1 = rr; if (i1 > 26) i1 = 26;
  int j0 = cc - 4; if (j0 < 0) j0 = 0; j0 += (j0 & 1);
  int j1 = cc; if (j1 > 26) j1 = 26;
  for (int i = i0; i <= i1; i += 2)
    for (int jj = j0; jj <= j1; jj += 2) {
      int e = b * 196 + (i >> 1) * 14 + (jj >> 1);
      acc += s_loc[(size_t)e * CH + c];
    }
  float zv = acc * dv2_of(ub);
  z[(size_t)ub * CH + c] = zv;

  __shared__ float ls[4][CH], ls2[4][CH];
  ls[w][c] = zv; ls2[w][c] = zv * zv;
  __syncthreads();
  if (threadIdx.x < 64) {
    int bin = (blockIdx.x & 7) * CH;
    atomicAdd(&gsum[bin + c],   ls[0][c] + ls[1][c] + ls[2][c] + ls[3][c]);
    atomicAdd(&gsumsq[bin + c], ls2[0][c] + ls2[1][c] + ls2[2][c] + ls2[3][c]);
  }
}

// ---------- K7: BN finalize (8 bins, per-thread) + apply + relu + residual ----------
__global__ void k_out(const float* __restrict__ z, const float* __restrict__ X,
                      const float* __restrict__ gsum, const float* __restrict__ gsumsq,
                      const float* __restrict__ gamma, const float* __restrict__ beta,
                      float* __restrict__ out) {
  int c = threadIdx.x & 63;
  int w = threadIdx.x >> 6;
  float S = 0.f, S2 = 0.f;
  #pragma unroll
  for (int b = 0; b < 8; ++b) {
    S  += gsum[b * CH + c];
    S2 += gsumsq[b * CH + c];
  }
  float m = S * (1.0f / (float)BNTOT);
  float var = S2 * (1.0f / (float)BNTOT) - m * m;
  float rstd = 1.0f / sqrtf(var + 1e-5f);

  int u = blockIdx.x * 4 + w;
  size_t idx = (size_t)u * CH + c;
  float zn = (z[idx] - m) * rstd * gamma[c] + beta[c];
  out[idx] = fmaxf(zn, 0.f) + X[idx];
}

// ---------- launch ----------
extern "C" void kernel_launch(void* const* d_in, const int* in_sizes, int n_in,
                              void* d_out, int out_size, void* d_ws, size_t ws_size,
                              hipStream_t stream) {
  const float* X     = (const float*)d_in[0];
  const float* W     = (const float*)d_in[1];
  const float* bias  = (const float*)d_in[2];
  const float* gamma = (const float*)d_in[3];
  const float* beta  = (const float*)d_in[4];
  float* out = (float*)d_out;

  // workspace layout
  float* ws = (float*)d_ws;
  float* sq      = ws;                        // 8192
  float* thr     = sq + 8192;                 // 8192
  float* t       = thr + 8192;                // 524288
  float* s_loc   = t + 524288;                // 100352
  float* z       = s_loc + 100352;            // 524288
  float* thrpart = z + 524288;                // 1024*64*11 = 720896
  int*   inds    = (int*)(thrpart + 720896);  // 90112 ints
  unsigned short* Xh = (unsigned short*)(inds + 90112);            // 524288 shorts
  unsigned long long* mask = (unsigned long long*)(Xh + 524288);   // 8192*128 u64 = 8 MB
  // zeroed region: DE (8192 int) + gsum/gsumsq (8 bins x 64 each) + s_knn
  int*   DE     = (int*)(mask + (size_t)8192 * 128);
  float* gsum   = (float*)(DE + 8192);        // 512
  float* gsumsq = gsum + 512;                 // 512
  float* s_knn  = gsumsq + 512;               // 524288

  hipMemsetAsync(DE, 0, (size_t)(8192 + 512 + 512 + 524288) * 4, stream);

  k_cast    <<<2048, 256, 0, stream>>>(X, Xh, sq);
  k_thrpart <<<1024, 256, 0, stream>>>(X, sq, thrpart);
  k_thrmerge<<<128, 64, 0, stream>>>(thrpart, thr);
  k_filter  <<<4096, 256, 0, stream>>>(Xh, sq, thr, mask);
  k_rescore <<<2048, 256, 0, stream>>>(X, sq, mask, inds, DE);
  k_lin     <<<512, 256, 0, stream>>>(X, W, bias, t);
  k_edge    <<<BNTOT / 4 + NLOC / 4, 256, 0, stream>>>(t, inds, s_knn, s_loc);
  k_gatherbn<<<BNTOT / 4, 256, 0, stream>>>(s_knn, s_loc, inds, DE, z, gsum, gsumsq);
  k_out     <<<BNTOT / 4, 256, 0, stream>>>(z, X, gsum, gsumsq, gamma, beta, out);

  (void)in_sizes; (void)n_in; (void)out_size; (void)ws_size;
}